// Round 4
// baseline (97.402 us; speedup 1.0000x reference)
//
#include <hip/hip_runtime.h>
#include <stdint.h>

// TopKLayer quirky sparse_hw: per row (3136 elems), t = spatial index of the
// k-th largest |x| (k=313, ties by ascending index); keep the t smallest-|x|
// elements (stable). ONE WAVE PER ROW, no __syncthreads: per-wave LDS slice,
// same-wave DS ops are in-order. Row re-read from global (L2/L3-warm).
// 2048-bin packed u16 histogram -> candidate compaction -> 256-bin refinement.

#define HW     3136
#define NW4    784        // HW/4
#define WPB    4          // waves (rows) per 256-thread block
#define NT     256
#define KSEL   313u
#define NB0WP  1088       // 1024 packed words + pad every 16
#define NB2WP  136        // 128 packed words + pad
#define CAP    320        // candidate bin capacity (stat max ~190)
#define CAP2   64         // sub-bin tie capacity

#define OFF_H0   0
#define OFF_CAND 1088
#define OFF_H2   1408
#define OFF_CNT  1544
#define OFF_SCR  1545
#define OFF_TINY 1546
#define WW       1616     // words per wave slice (6464 B)

#define PADW(w) ((w) + ((w) >> 4))

__device__ __forceinline__ unsigned wscan(unsigned v) {
    const int lane = threadIdx.x & 63;
#pragma unroll
    for (int d = 1; d < 64; d <<= 1) {
        unsigned o = __shfl_up(v, d, 64);
        if (lane >= d) v += o;
    }
    return v;
}

__device__ __forceinline__ unsigned h16(const unsigned* h, unsigned bin) {
    unsigned w = h[PADW(bin >> 1)];
    return (bin & 1) ? (w >> 16) : (w & 0xFFFFu);
}

__device__ __forceinline__ void hadd(unsigned* h, unsigned bin) {
    atomicAdd((unsigned*)&h[PADW(bin >> 1)], (bin & 1) ? 0x10000u : 1u);
}

// Locate bin holding dir-rank m over a packed u16 histogram of SEGW*2*64 bins.
// Lane covers SEGW words (SEGW*2 bins). Returns bin and 1-based rank within it.
template <int SEGW, bool fromTop>
__device__ void locate(const unsigned* h, unsigned m, unsigned& bOut, unsigned& mOut) {
    const int lane = threadIdx.x & 63;
    const int seg = fromTop ? (63 - lane) : lane;
    unsigned s = 0;
#pragma unroll
    for (int i = 0; i < SEGW; ++i) {
        unsigned w = h[PADW(seg * SEGW + i)];
        s += (w & 0xFFFFu) + (w >> 16);
    }
    unsigned S = wscan(s);
    unsigned long long bal = __ballot(S >= m);
    int fl = __ffsll(bal) - 1;
    unsigned packed = 0;
    if (lane == fl) {
        unsigned rem = m - (S - s);
        unsigned acc = 0;
        const int nb = SEGW * 2;
        for (int i = 0; i < nb; ++i) {
            unsigned bin = fromTop ? (unsigned)(seg * nb + nb - 1 - i)
                                   : (unsigned)(seg * nb + i);
            unsigned hh = h16(h, bin);
            acc += hh;
            if (acc >= rem) { packed = (bin << 16) | (rem - (acc - hh)); break; }
        }
    }
    packed = __shfl(packed, fl, 64);
    bOut = packed >> 16;
    mOut = packed & 0xFFFFu;
}

// mm-th (ascending index) occurrence of exact key K in the row. (fallback)
__device__ unsigned occ_scan(unsigned* wl, const uint4* xin, unsigned K, unsigned mm) {
    const int lane = threadIdx.x & 63;
    unsigned prev = 0;
    for (int it = 0; it < 13; ++it) {
        int j = it * 64 + lane;
        unsigned lm = 0;
        if (j < NW4) {
            uint4 v = xin[j];
            lm  = ((v.x & 0x7fffffffu) == K) ? 1u : 0u;
            lm |= ((v.y & 0x7fffffffu) == K) ? 2u : 0u;
            lm |= ((v.z & 0x7fffffffu) == K) ? 4u : 0u;
            lm |= ((v.w & 0x7fffffffu) == K) ? 8u : 0u;
        }
        unsigned c = __popc(lm);
        unsigned S = wscan(c);
        unsigned tot = __shfl(S, 63, 64);
        unsigned ex = prev + S - c;
        if (lm && ex < mm && mm <= ex + c) {
            unsigned need = mm - ex, s2 = 0, bit = 0;
            for (bit = 0; bit < 4; ++bit)
                if (lm & (1u << bit)) { if (++s2 == need) break; }
            wl[OFF_SCR] = (unsigned)(j * 4) + bit;
        }
        prev += tot;
        if (prev >= mm) break;
    }
    return wl[OFF_SCR];
}

// fallback refinement level over full row (rare). Updates m, outputs digit.
template <bool fromTop>
__device__ void refine_level(unsigned* wl, const uint4* xin, unsigned pfx, int pshift,
                             int bshift, unsigned bmask, unsigned& m, unsigned& dout) {
    unsigned* h2 = wl + OFF_H2;
    const int lane = threadIdx.x & 63;
    for (int i = lane; i < NB2WP; i += 64) h2[i] = 0;
    for (int it = 0; it < 13; ++it) {
        int j = it * 64 + lane;
        if (j < NW4) {
            uint4 v = xin[j];
            unsigned k;
            k = v.x & 0x7fffffffu; if ((k >> pshift) == pfx) hadd(h2, (k >> bshift) & bmask);
            k = v.y & 0x7fffffffu; if ((k >> pshift) == pfx) hadd(h2, (k >> bshift) & bmask);
            k = v.z & 0x7fffffffu; if ((k >> pshift) == pfx) hadd(h2, (k >> bshift) & bmask);
            k = v.w & 0x7fffffffu; if ((k >> pshift) == pfx) hadd(h2, (k >> bshift) & bmask);
        }
    }
    unsigned b2, m2;
    locate<2, fromTop>(h2, m, b2, m2);
    dout = b2; m = m2;
}

// Select dir-rank m among cnt compacted candidates (unique composites).
template <bool fromTop>
__device__ bool sel_cand(unsigned* wl, unsigned cnt, unsigned m, unsigned& cOut) {
    unsigned* h2 = wl + OFF_H2;
    unsigned* cand = wl + OFF_CAND;
    const int lane = threadIdx.x & 63;
    for (int i = lane; i < NB2WP; i += 64) h2[i] = 0;
    for (int i = lane; i < (int)cnt; i += 64) hadd(h2, cand[i] >> 24);
    unsigned b2, m2;
    locate<2, fromTop>(h2, m, b2, m2);
    if (lane == 0) wl[OFF_SCR] = 0;
    for (int i = lane; i < (int)cnt; i += 64) {
        unsigned c = cand[i];
        if ((c >> 24) == b2) {
            unsigned p = atomicAdd((unsigned*)&wl[OFF_SCR], 1u);
            if (p < CAP2) wl[OFF_TINY + p] = c;
        }
    }
    unsigned c2 = wl[OFF_SCR];
    if (c2 > CAP2) return false;
    unsigned res = wl[OFF_TINY];  // c2 == 1 common case (m2 == 1)
    if (c2 > 1) {
        if (lane == 0) {
            for (unsigned i = 0; i < c2; ++i) {
                unsigned ci = wl[OFF_TINY + i];
                unsigned di = fromTop ? (ci ^ 0xFFFu) : ci;
                unsigned r = 1;
                for (unsigned jj = 0; jj < c2; ++jj) {
                    unsigned dj = fromTop ? (wl[OFF_TINY + jj] ^ 0xFFFu) : wl[OFF_TINY + jj];
                    if (fromTop ? (dj > di) : (dj < di)) r++;
                }
                if (r == m2) res = ci;
            }
        }
        res = __shfl(res, 0, 64);
    }
    cOut = res;
    return true;
}

// dir-rank m over the whole row -> exact 31-bit key + spatial index.
template <bool fromTop>
__device__ void wave_select(unsigned* wl, const uint4* xin, unsigned m,
                            unsigned& keyOut, unsigned& eOut) {
    const int lane = threadIdx.x & 63;
    unsigned b0, m1;
    locate<16, fromTop>(wl + OFF_H0, m, b0, m1);
    if (lane == 0) wl[OFF_CNT] = 0;
    unsigned* cand = wl + OFF_CAND;
    for (int it = 0; it < 13; ++it) {
        int j = it * 64 + lane;
        if (j < NW4) {
            uint4 v = xin[j];
            unsigned i0 = 4u * (unsigned)j;
            unsigned k, p;
            k = v.x & 0x7fffffffu;
            if ((k >> 20) == b0) { p = atomicAdd((unsigned*)&wl[OFF_CNT], 1u); if (p < CAP) cand[p] = ((k & 0xFFFFFu) << 12) | i0; }
            k = v.y & 0x7fffffffu;
            if ((k >> 20) == b0) { p = atomicAdd((unsigned*)&wl[OFF_CNT], 1u); if (p < CAP) cand[p] = ((k & 0xFFFFFu) << 12) | (i0 + 1u); }
            k = v.z & 0x7fffffffu;
            if ((k >> 20) == b0) { p = atomicAdd((unsigned*)&wl[OFF_CNT], 1u); if (p < CAP) cand[p] = ((k & 0xFFFFFu) << 12) | (i0 + 2u); }
            k = v.w & 0x7fffffffu;
            if ((k >> 20) == b0) { p = atomicAdd((unsigned*)&wl[OFF_CNT], 1u); if (p < CAP) cand[p] = ((k & 0xFFFFFu) << 12) | (i0 + 3u); }
        }
    }
    unsigned cnt = wl[OFF_CNT];
    if (cnt <= CAP) {
        unsigned c;
        if (sel_cand<fromTop>(wl, cnt, m1, c)) {
            keyOut = (b0 << 20) | (c >> 12);
            eOut = c & 0xFFFu;
            return;
        }
    }
    // pathological fallback: 8/8/4-bit refinement + occurrence scan
    unsigned d1, d2, d3, mm = m1;
    refine_level<fromTop>(wl, xin, b0, 20, 12, 0xFFu, mm, d1);
    refine_level<fromTop>(wl, xin, (b0 << 8) | d1, 12, 4, 0xFFu, mm, d2);
    refine_level<fromTop>(wl, xin, (b0 << 16) | (d1 << 8) | d2, 4, 0, 0xFu, mm, d3);
    unsigned K = (((b0 << 16) | (d1 << 8) | d2) << 4) | d3;
    keyOut = K;
    eOut = occ_scan(wl, xin, K, mm);
}

extern "C" __global__ void __launch_bounds__(NT)
topk_kernel(const float* __restrict__ x, float* __restrict__ out) {
    __shared__ unsigned lds[WPB * WW];  // 25856 B -> 6 blocks/CU (24 waves, 75%)
    const int lane = threadIdx.x & 63;
    const int wid = threadIdx.x >> 6;
    const int row = blockIdx.x * WPB + wid;
    unsigned* wl = lds + wid * WW;
    const uint4* __restrict__ xin = (const uint4*)(x + (size_t)row * HW);
    uint4* __restrict__ xout = (uint4*)(out + (size_t)row * HW);

    unsigned* h0 = wl + OFF_H0;
    for (int i = lane; i < NB0WP; i += 64) h0[i] = 0;
    for (int it = 0; it < 13; ++it) {
        int j = it * 64 + lane;
        if (j < NW4) {
            uint4 v = xin[j];
            hadd(h0, (v.x & 0x7fffffffu) >> 20);
            hadd(h0, (v.y & 0x7fffffffu) >> 20);
            hadd(h0, (v.z & 0x7fffffffu) >> 20);
            hadd(h0, (v.w & 0x7fffffffu) >> 20);
        }
    }

    // Select A: k-th largest -> spatial index tIdx (= keep count)
    unsigned KA, tIdx;
    wave_select<true>(wl, xin, KSEL, KA, tIdx);

    if (tIdx == 0) {
        uint4 z = make_uint4(0u, 0u, 0u, 0u);
        for (int it = 0; it < 13; ++it) {
            int j = it * 64 + lane;
            if (j < NW4) xout[j] = z;
        }
        return;
    }

    // Select B: tIdx-th smallest (stable) -> threshold key KB, cutoff index eB
    unsigned KB, eB;
    wave_select<false>(wl, xin, tIdx, KB, eB);

    // keep = key < KB || (key == KB && idx <= eB)
    for (int it = 0; it < 13; ++it) {
        int j = it * 64 + lane;
        if (j < NW4) {
            uint4 v = xin[j];
            unsigned i0 = 4u * (unsigned)j;
            unsigned k;
            k = v.x & 0x7fffffffu; if (!(k < KB || (k == KB && i0      <= eB))) v.x = 0u;
            k = v.y & 0x7fffffffu; if (!(k < KB || (k == KB && i0 + 1u <= eB))) v.y = 0u;
            k = v.z & 0x7fffffffu; if (!(k < KB || (k == KB && i0 + 2u <= eB))) v.z = 0u;
            k = v.w & 0x7fffffffu; if (!(k < KB || (k == KB && i0 + 3u <= eB))) v.w = 0u;
            xout[j] = v;
        }
    }
}

extern "C" void kernel_launch(void* const* d_in, const int* in_sizes, int n_in,
                              void* d_out, int out_size, void* d_ws, size_t ws_size,
                              hipStream_t stream) {
    const float* x = (const float*)d_in[0];
    float* out = (float*)d_out;
    const int rows = in_sizes[0] / HW;          // 8192
    topk_kernel<<<dim3(rows / WPB), dim3(NT), 0, stream>>>(x, out);
}

// Round 5
// 82.091 us; speedup vs baseline: 1.1865x; 1.1865x over previous
//
#include <hip/hip_runtime.h>
#include <stdint.h>

// TopKLayer quirky sparse_hw: per row (3136 elems), t = spatial index of the
// k-th largest |x| (k=313, ties ascending index); keep the t smallest-|x|
// elements (stable). Block-per-row, row staged in LDS once. Packed-u16
// 2048-bin histogram; locate/rank phases run on wave 0 only (no barriers
// inside a wave); candidates ranked via 256-bin sub-histogram.

#define HW    3136
#define NW4   784        // HW/4
#define NT    256
#define KSEL  313u
#define CAP   320        // candidate bin capacity (stat max ~190)
#define CAP2  64         // tie-set capacity

#define PADW(w) ((w) + ((w) >> 4))

__device__ __forceinline__ unsigned wscan(unsigned v) {
    const int lane = threadIdx.x & 63;
#pragma unroll
    for (int d = 1; d < 64; d <<= 1) {
        unsigned o = __shfl_up(v, d, 64);
        if (lane >= d) v += o;
    }
    return v;
}

__device__ __forceinline__ unsigned h16(const unsigned* h, unsigned bin) {
    unsigned w = h[PADW(bin >> 1)];
    return (bin & 1) ? (w >> 16) : (w & 0xFFFFu);
}

__device__ __forceinline__ void hadd(unsigned* h, unsigned bin) {
    atomicAdd(&h[PADW(bin >> 1)], (bin & 1) ? 0x10000u : 1u);
}

// Wave-internal: locate bin holding dir-rank m in packed u16 hist of
// SEGW*2*64 bins. All lanes of the calling wave get (bin, rank-within-bin).
template <int SEGW, bool fromTop>
__device__ void locate(const unsigned* h, unsigned m, unsigned& bOut, unsigned& mOut) {
    const int lane = threadIdx.x & 63;
    const int seg = fromTop ? (63 - lane) : lane;
    unsigned s = 0;
#pragma unroll
    for (int i = 0; i < SEGW; ++i) {
        unsigned w = h[PADW(seg * SEGW + i)];
        s += (w & 0xFFFFu) + (w >> 16);
    }
    unsigned S = wscan(s);
    unsigned long long bal = __ballot(S >= m);
    int fl = __ffsll(bal) - 1;
    unsigned packed = 0;
    if (lane == fl) {
        unsigned rem = m - (S - s);
        unsigned acc = 0;
        const int nb = SEGW * 2;
        for (int i = 0; i < nb; ++i) {
            unsigned bin = fromTop ? (unsigned)(seg * nb + nb - 1 - i)
                                   : (unsigned)(seg * nb + i);
            unsigned hh = h16(h, bin);
            acc += hh;
            if (acc >= rem) { packed = (bin << 16) | (rem - (acc - hh)); break; }
        }
    }
    packed = __shfl(packed, fl, 64);
    bOut = packed >> 16;
    mOut = packed & 0xFFFFu;
}

// Wave0-only: rank dir-m among cnt compacted candidates via 256-bin
// sub-histogram (bins = composite bits 31..24). Writes s_b[2] (result) or
// s_b[4]=1 (tie overflow -> fallback).
template <bool fromTop>
__device__ void rank_cand_wave(unsigned* h2, const unsigned* cand, unsigned* tiny,
                               unsigned* s_b, unsigned cnt, unsigned m) {
    const int lane = threadIdx.x & 63;
    for (int i = lane; i < 136; i += 64) h2[i] = 0;
    for (int i = lane; i < (int)cnt; i += 64) hadd(h2, cand[i] >> 24);
    unsigned b2, m2;
    locate<2, fromTop>(h2, m, b2, m2);
    if (lane == 0) s_b[5] = 0;
    for (int i = lane; i < (int)cnt; i += 64) {
        unsigned c = cand[i];
        if ((c >> 24) == b2) {
            unsigned p = atomicAdd(&s_b[5], 1u);
            if (p < CAP2) tiny[p] = c;
        }
    }
    unsigned c2 = s_b[5];
    if (c2 > CAP2) { if (lane == 0) s_b[4] = 1u; return; }
    if (lane < (int)c2) {
        unsigned ci = tiny[lane];
        unsigned di = fromTop ? (ci ^ 0xFFFu) : ci;
        unsigned r = 1;
        for (unsigned j = 0; j < c2; ++j) {
            unsigned dj = fromTop ? (tiny[j] ^ 0xFFFu) : tiny[j];
            if (fromTop ? (dj > di) : (dj < di)) r++;
        }
        if (r == m2) s_b[2] = ci;  // unique rank -> single writer
    }
}

// Block-wide: dir-rank `rank` over the row -> exact 31-bit key + spatial idx.
template <bool fromTop>
__device__ void block_select(const uint4* s_x4, const unsigned* s_h0,
                             unsigned* s_cand, unsigned* s_h2, unsigned* s_tiny,
                             unsigned* s_b, unsigned rank,
                             unsigned& keyOut, unsigned& eOut) {
    const int t = threadIdx.x;
    const int lane = t & 63;
    const int wid = t >> 6;

    if (wid == 0) {
        unsigned b0, m1;
        locate<16, fromTop>(s_h0, rank, b0, m1);
        if (lane == 0) { s_b[0] = b0; s_b[1] = m1; s_b[3] = 0; s_b[4] = 0; }
    }
    __syncthreads();
    const unsigned b0 = s_b[0];
    const unsigned m1 = s_b[1];

    // compact candidate bin from the LDS row: composite (low20<<12)|idx
    for (int j = t; j < NW4; j += NT) {
        uint4 v = s_x4[j];
        const unsigned i0 = 4u * (unsigned)j;
        unsigned k, p;
        k = v.x & 0x7fffffffu;
        if ((k >> 20) == b0) { p = atomicAdd(&s_b[3], 1u); if (p < CAP) s_cand[p] = ((k & 0xFFFFFu) << 12) | i0; }
        k = v.y & 0x7fffffffu;
        if ((k >> 20) == b0) { p = atomicAdd(&s_b[3], 1u); if (p < CAP) s_cand[p] = ((k & 0xFFFFFu) << 12) | (i0 + 1u); }
        k = v.z & 0x7fffffffu;
        if ((k >> 20) == b0) { p = atomicAdd(&s_b[3], 1u); if (p < CAP) s_cand[p] = ((k & 0xFFFFFu) << 12) | (i0 + 2u); }
        k = v.w & 0x7fffffffu;
        if ((k >> 20) == b0) { p = atomicAdd(&s_b[3], 1u); if (p < CAP) s_cand[p] = ((k & 0xFFFFFu) << 12) | (i0 + 3u); }
    }
    __syncthreads();
    const unsigned cnt = s_b[3];

    bool needFallback;
    if (cnt <= CAP) {
        if (wid == 0) rank_cand_wave<fromTop>(s_h2, s_cand, s_tiny, s_b, cnt, m1);
        __syncthreads();
        needFallback = (s_b[4] != 0);
    } else {
        needFallback = true;
    }

    if (!needFallback) {
        const unsigned c = s_b[2];
        keyOut = (b0 << 20) | (c >> 12);
        eOut = c & 0xFFFu;
        return;
    }

    // pathological fallback: counting rank over the full row, bin-filtered
    const unsigned* s_x = (const unsigned*)s_x4;
    for (int j = t; j < HW; j += NT) {
        const unsigned k = s_x[j] & 0x7fffffffu;
        if ((k >> 20) != b0) continue;
        unsigned Ci = ((k & 0xFFFFFu) << 12) | (unsigned)j;
        if (fromTop) Ci ^= 0xFFFu;
        unsigned r = 1;
        for (int j2 = 0; j2 < HW; ++j2) {
            const unsigned k2 = s_x[j2] & 0x7fffffffu;
            if ((k2 >> 20) != b0) continue;
            unsigned Cj = ((k2 & 0xFFFFFu) << 12) | (unsigned)j2;
            if (fromTop) Cj ^= 0xFFFu;
            if (fromTop ? (Cj > Ci) : (Cj < Ci)) r++;
        }
        if (r == m1) s_b[2] = ((k & 0xFFFFFu) << 12) | (unsigned)j;
    }
    __syncthreads();
    const unsigned c = s_b[2];
    keyOut = (b0 << 20) | (c >> 12);
    eOut = c & 0xFFFu;
}

extern "C" __global__ void __launch_bounds__(NT)
topk_kernel(const float* __restrict__ x, float* __restrict__ out) {
    __shared__ uint4 s_x4[NW4];         // 12544 B
    __shared__ unsigned s_h0[1088];     //  4352 B (1024 packed u16 words + pad)
    __shared__ unsigned s_cand[CAP];    //  1280 B
    __shared__ unsigned s_h2[136];      //   544 B
    __shared__ unsigned s_tiny[CAP2];   //   256 B
    __shared__ unsigned s_b[8];
    // total ~19 KB -> 8 blocks/CU (32 waves, 100% theoretical)

    const int t = threadIdx.x;
    const int row = blockIdx.x;
    const uint4* __restrict__ xin = (const uint4*)(x + (size_t)row * HW);
    uint4* __restrict__ xout = (uint4*)(out + (size_t)row * HW);

    for (int i = t; i < 1088; i += NT) s_h0[i] = 0;
    __syncthreads();
    // fused load + histogram (top 11 bits of abs key)
    for (int j = t; j < NW4; j += NT) {
        uint4 v = xin[j];
        s_x4[j] = v;
        hadd(s_h0, (v.x & 0x7fffffffu) >> 20);
        hadd(s_h0, (v.y & 0x7fffffffu) >> 20);
        hadd(s_h0, (v.z & 0x7fffffffu) >> 20);
        hadd(s_h0, (v.w & 0x7fffffffu) >> 20);
    }
    __syncthreads();

    // Select A: k-th largest -> spatial index tIdx (= keep count)
    unsigned KA, tIdx;
    block_select<true>(s_x4, s_h0, s_cand, s_h2, s_tiny, s_b, KSEL, KA, tIdx);

    if (tIdx == 0) {  // keep nothing
        uint4 z = make_uint4(0u, 0u, 0u, 0u);
        for (int j = t; j < NW4; j += NT) xout[j] = z;
        return;
    }

    // Select B: tIdx-th smallest (stable) -> threshold key KB, cutoff index eB
    unsigned KB, eB;
    block_select<false>(s_x4, s_h0, s_cand, s_h2, s_tiny, s_b, tIdx, KB, eB);

    // keep = key < KB || (key == KB && idx <= eB)
    for (int j = t; j < NW4; j += NT) {
        uint4 v = s_x4[j];
        const unsigned i0 = 4u * (unsigned)j;
        unsigned k;
        k = v.x & 0x7fffffffu; if (!(k < KB || (k == KB && i0      <= eB))) v.x = 0u;
        k = v.y & 0x7fffffffu; if (!(k < KB || (k == KB && i0 + 1u <= eB))) v.y = 0u;
        k = v.z & 0x7fffffffu; if (!(k < KB || (k == KB && i0 + 2u <= eB))) v.z = 0u;
        k = v.w & 0x7fffffffu; if (!(k < KB || (k == KB && i0 + 3u <= eB))) v.w = 0u;
        xout[j] = v;
    }
}

extern "C" void kernel_launch(void* const* d_in, const int* in_sizes, int n_in,
                              void* d_out, int out_size, void* d_ws, size_t ws_size,
                              hipStream_t stream) {
    const float* x = (const float*)d_in[0];
    float* out = (float*)d_out;
    const int rows = in_sizes[0] / HW;  // 8192
    topk_kernel<<<dim3(rows), dim3(NT), 0, stream>>>(x, out);
}

// Round 6
// 62.921 us; speedup vs baseline: 1.5480x; 1.3047x over previous
//
#include <hip/hip_runtime.h>
#include <stdint.h>

// TopKLayer quirky sparse_hw: per row (3136 elems), t = spatial index of the
// k-th largest |x| (k=313, ties ascending index); keep the t smallest-|x|
// elements (stable). Block-per-row, row staged in LDS. 2048-bin histogram
// with REGISTER-RESIDENT exclusive CDF (thread t owns bins 8t..8t+7): both
// selections locate their bin with an O(1) register check. Candidate rank via
// one-bin-per-thread 256-bin sub-histogram + register CDF + tiny tie-set.

#define HW    3136
#define NW4   784        // HW/4
#define NT    256
#define KSEL  313u
#define CAP   320        // candidate bin capacity (stat max ~190)
#define CAP2  64         // tie-set capacity
#define O_CAND 0         // reuse offsets inside s_h (free after CDF phase)
#define O_HC   384
#define O_TINY 704

__device__ __forceinline__ unsigned wscan(unsigned v) {
    const int lane = threadIdx.x & 63;
#pragma unroll
    for (int d = 1; d < 64; d <<= 1) {
        unsigned o = __shfl_up(v, d, 64);
        if (lane >= d) v += o;
    }
    return v;
}

// Finish a selection once bin b0 and within-bin dir-rank m1 are known.
// Returns composite (low20<<12)|idx of the selected element.
template <bool fromTop>
__device__ unsigned select_finish(const uint4* s_x4, unsigned* s_h,
                                  unsigned* s_warp, unsigned* s_b,
                                  unsigned b0, unsigned m1) {
    const int t = threadIdx.x;
    const int lane = t & 63;
    const int wid = t >> 6;
    unsigned* cand = s_h + O_CAND;

    // compact candidate bin from LDS row: composite (low20<<12)|idx
    for (int j = t; j < NW4; j += NT) {
        uint4 v = s_x4[j];
        const unsigned i0 = 4u * (unsigned)j;
        unsigned k, p;
        k = v.x & 0x7fffffffu;
        if ((k >> 20) == b0) { p = atomicAdd(&s_b[3], 1u); if (p < CAP) cand[p] = ((k & 0xFFFFFu) << 12) | i0; }
        k = v.y & 0x7fffffffu;
        if ((k >> 20) == b0) { p = atomicAdd(&s_b[3], 1u); if (p < CAP) cand[p] = ((k & 0xFFFFFu) << 12) | (i0 + 1u); }
        k = v.z & 0x7fffffffu;
        if ((k >> 20) == b0) { p = atomicAdd(&s_b[3], 1u); if (p < CAP) cand[p] = ((k & 0xFFFFFu) << 12) | (i0 + 2u); }
        k = v.w & 0x7fffffffu;
        if ((k >> 20) == b0) { p = atomicAdd(&s_b[3], 1u); if (p < CAP) cand[p] = ((k & 0xFFFFFu) << 12) | (i0 + 3u); }
    }
    __syncthreads();
    const unsigned cnt = s_b[3];
    bool fb = (cnt > CAP);

    if (!fb) {
        unsigned* hc = s_h + O_HC;   // 256-bin sub-hist over composite bits 31:24
        hc[t] = 0;
        if (t == 0) s_b[5] = 0;
        __syncthreads();
        for (int i = t; i < (int)cnt; i += NT) atomicAdd(&hc[cand[i] >> 24], 1u);
        __syncthreads();
        const unsigned sc = hc[t];   // thread t owns sub-bin t
        unsigned Sic = wscan(sc);
        if (lane == 63) s_warp[wid] = Sic;
        __syncthreads();
        unsigned crossc = 0;
        for (int w2 = 0; w2 < wid; ++w2) crossc += s_warp[w2];
        const unsigned cdf2 = crossc + Sic - sc;  // exclusive CDF of sub-bin t
        bool hit;
        unsigned m2c = 0;
        if (fromTop) {
            const unsigned suf2 = cnt - cdf2 - sc;
            hit = (suf2 < m1 && m1 <= suf2 + sc);
            if (hit) m2c = m1 - suf2;
        } else {
            hit = (cdf2 < m1 && m1 <= cdf2 + sc);
            if (hit) m2c = m1 - cdf2;
        }
        if (hit) { s_b[0] = (unsigned)t; s_b[1] = m2c; }
        __syncthreads();
        const unsigned b2 = s_b[0];
        const unsigned m2 = s_b[1];
        unsigned* tiny = s_h + O_TINY;
        for (int i = t; i < (int)cnt; i += NT) {
            const unsigned cc = cand[i];
            if ((cc >> 24) == b2) { const unsigned p = atomicAdd(&s_b[5], 1u); if (p < CAP2) tiny[p] = cc; }
        }
        __syncthreads();
        const unsigned c2 = s_b[5];
        if (c2 > CAP2) fb = true;
        else {
            if (t < (int)c2) {   // rank within tie-set (c2 == 1 common case)
                const unsigned ci = tiny[t];
                const unsigned di = fromTop ? (ci ^ 0xFFFu) : ci;
                unsigned r = 1;
                for (unsigned j = 0; j < c2; ++j) {
                    const unsigned dj = fromTop ? (tiny[j] ^ 0xFFFu) : tiny[j];
                    if (fromTop ? (dj > di) : (dj < di)) r++;
                }
                if (r == m2) s_b[2] = ci;
            }
            __syncthreads();
        }
    }

    if (fb) {  // pathological fallback: bin-filtered counting rank, full row
        const unsigned* s_x = (const unsigned*)s_x4;
        for (int j = t; j < HW; j += NT) {
            const unsigned k = s_x[j] & 0x7fffffffu;
            if ((k >> 20) != b0) continue;
            unsigned Ci = ((k & 0xFFFFFu) << 12) | (unsigned)j;
            if (fromTop) Ci ^= 0xFFFu;
            unsigned r = 1;
            for (int j2 = 0; j2 < HW; ++j2) {
                const unsigned k2 = s_x[j2] & 0x7fffffffu;
                if ((k2 >> 20) != b0) continue;
                unsigned Cj = ((k2 & 0xFFFFFu) << 12) | (unsigned)j2;
                if (fromTop) Cj ^= 0xFFFu;
                if (fromTop ? (Cj > Ci) : (Cj < Ci)) r++;
            }
            if (r == m1) s_b[2] = ((k & 0xFFFFFu) << 12) | (unsigned)j;
        }
        __syncthreads();
    }
    return s_b[2];
}

extern "C" __global__ void __launch_bounds__(NT)
topk_kernel(const float* __restrict__ x, float* __restrict__ out) {
    __shared__ uint4 s_x4[NW4];     // 12544 B
    __shared__ uint4 s_h4[512];     //  8192 B (2048-bin hist, reused after CDF)
    __shared__ unsigned s_warp[4];
    __shared__ unsigned s_b[8];
    unsigned* s_h = (unsigned*)s_h4;

    const int t = threadIdx.x;
    const int lane = t & 63;
    const int wid = t >> 6;
    const int row = blockIdx.x;
    const uint4* __restrict__ xin = (const uint4*)(x + (size_t)row * HW);
    uint4* __restrict__ xout = (uint4*)(out + (size_t)row * HW);

    {
        uint4 z = make_uint4(0u, 0u, 0u, 0u);
        s_h4[t] = z;
        s_h4[t + NT] = z;
    }
    __syncthreads();
    // fused load + 2048-bin histogram (abs-key bits 30:20)
    for (int j = t; j < NW4; j += NT) {
        uint4 v = xin[j];
        s_x4[j] = v;
        atomicAdd(&s_h[(v.x & 0x7fffffffu) >> 20], 1u);
        atomicAdd(&s_h[(v.y & 0x7fffffffu) >> 20], 1u);
        atomicAdd(&s_h[(v.z & 0x7fffffffu) >> 20], 1u);
        atomicAdd(&s_h[(v.w & 0x7fffffffu) >> 20], 1u);
    }
    __syncthreads();

    // register-resident CDF: thread t owns bins 8t..8t+7
    const uint4 ca = s_h4[2 * t];
    const uint4 cb = s_h4[2 * t + 1];
    unsigned c[8] = {ca.x, ca.y, ca.z, ca.w, cb.x, cb.y, cb.z, cb.w};
    unsigned pre[8];
    unsigned ssum = 0;
#pragma unroll
    for (int i = 0; i < 8; ++i) { pre[i] = ssum; ssum += c[i]; }
    unsigned Si = wscan(ssum);
    if (lane == 63) s_warp[wid] = Si;
    __syncthreads();
    unsigned cross = 0;
    for (int w2 = 0; w2 < wid; ++w2) cross += s_warp[w2];
    const unsigned base = cross + Si - ssum;  // exclusive CDF of bin 8t

    // ---- Select A: KSEL-th largest -> spatial index tIdx ----
    if (t == 0) s_b[3] = 0;
#pragma unroll
    for (int i = 0; i < 8; ++i) {
        const unsigned cdfb = base + pre[i];
        const unsigned suf = HW - cdfb - c[i];   // # elements in higher bins
        if (suf < KSEL && KSEL <= suf + c[i]) {
            s_b[0] = 8u * (unsigned)t + (unsigned)i;
            s_b[1] = KSEL - suf;
        }
    }
    __syncthreads();
    const unsigned b0A = s_b[0];
    const unsigned m1A = s_b[1];
    const unsigned compA = select_finish<true>(s_x4, s_h, s_warp, s_b, b0A, m1A);
    const unsigned tIdx = compA & 0xFFFu;

    if (tIdx == 0) {  // keep nothing
        uint4 z = make_uint4(0u, 0u, 0u, 0u);
        for (int j = t; j < NW4; j += NT) xout[j] = z;
        return;
    }

    // ---- Select B: tIdx-th smallest -> threshold KB, cutoff index eB ----
    if (t == 0) s_b[3] = 0;
#pragma unroll
    for (int i = 0; i < 8; ++i) {
        const unsigned cdfb = base + pre[i];
        if (cdfb < tIdx && tIdx <= cdfb + c[i]) {
            s_b[0] = 8u * (unsigned)t + (unsigned)i;
            s_b[1] = tIdx - cdfb;
        }
    }
    __syncthreads();
    const unsigned b0B = s_b[0];
    const unsigned m1B = s_b[1];
    const unsigned compB = select_finish<false>(s_x4, s_h, s_warp, s_b, b0B, m1B);
    const unsigned KB = (b0B << 20) | (compB >> 12);
    const unsigned eB = compB & 0xFFFu;

    // keep = key < KB || (key == KB && idx <= eB)
    for (int j = t; j < NW4; j += NT) {
        uint4 v = s_x4[j];
        const unsigned i0 = 4u * (unsigned)j;
        unsigned k;
        k = v.x & 0x7fffffffu; if (!(k < KB || (k == KB && i0      <= eB))) v.x = 0u;
        k = v.y & 0x7fffffffu; if (!(k < KB || (k == KB && i0 + 1u <= eB))) v.y = 0u;
        k = v.z & 0x7fffffffu; if (!(k < KB || (k == KB && i0 + 2u <= eB))) v.z = 0u;
        k = v.w & 0x7fffffffu; if (!(k < KB || (k == KB && i0 + 3u <= eB))) v.w = 0u;
        xout[j] = v;
    }
}

extern "C" void kernel_launch(void* const* d_in, const int* in_sizes, int n_in,
                              void* d_out, int out_size, void* d_ws, size_t ws_size,
                              hipStream_t stream) {
    const float* x = (const float*)d_in[0];
    float* out = (float*)d_out;
    const int rows = in_sizes[0] / HW;  // 8192
    topk_kernel<<<dim3(rows), dim3(NT), 0, stream>>>(x, out);
}

// Round 7
// 62.795 us; speedup vs baseline: 1.5511x; 1.0020x over previous
//
#include <hip/hip_runtime.h>
#include <stdint.h>

// TopKLayer quirky sparse_hw: per row (3136 elems), t = spatial index of the
// k-th largest |x| (k=313, ties ascending index); keep the t smallest-|x|
// elements (stable). Block-per-row. ROW LIVES IN REGISTERS (4 uint4/thread):
// load->regs, histogram from regs, candidate compaction from regs, final
// mask+store from regs. LDS only holds the 2048-bin histogram (reused for
// candidates / sub-hist / tie-set). Register-resident CDF locates bins O(1).

#define HW    3136
#define NW4   784        // HW/4
#define NT    256
#define KSEL  313u
#define CAP   320        // candidate bin capacity (stat max ~190)
#define CAP2  64         // tie-set capacity
#define O_CAND 0         // regions inside s_h (free after CDF phase)
#define O_HC   384
#define O_TINY 704

__device__ __forceinline__ unsigned wscan(unsigned v) {
    const int lane = threadIdx.x & 63;
#pragma unroll
    for (int d = 1; d < 64; d <<= 1) {
        unsigned o = __shfl_up(v, d, 64);
        if (lane >= d) v += o;
    }
    return v;
}

// Finish a selection once bin b0 and within-bin dir-rank m1 are known.
// Preconditions: s_b[3]=0, s_b[5]=0, hc region zeroed. Ends barrier-clean;
// re-zeroes hc for the next caller. Returns composite (low20<<12)|idx.
template <bool fromTop>
__device__ unsigned select_finish(uint4 v0, uint4 v1, uint4 v2, uint4 v3, bool has3,
                                  const unsigned* __restrict__ gx,
                                  unsigned* s_h, unsigned* s_warp, unsigned* s_b,
                                  unsigned b0, unsigned m1) {
    const int t = threadIdx.x;
    const int lane = t & 63;
    const int wid = t >> 6;
    unsigned* cand = s_h + O_CAND;
    unsigned* hc   = s_h + O_HC;

    // candidate compaction from registers: composite (low20<<12)|idx
    {
        auto put = [&](unsigned w, unsigned idx) {
            const unsigned k = w & 0x7fffffffu;
            if ((k >> 20) == b0) {
                const unsigned p = atomicAdd(&s_b[3], 1u);
                if (p < CAP) cand[p] = ((k & 0xFFFFFu) << 12) | idx;
            }
        };
        unsigned i0 = 4u * (unsigned)t;
        put(v0.x, i0); put(v0.y, i0 + 1u); put(v0.z, i0 + 2u); put(v0.w, i0 + 3u);
        i0 = 4u * (unsigned)(t + NT);
        put(v1.x, i0); put(v1.y, i0 + 1u); put(v1.z, i0 + 2u); put(v1.w, i0 + 3u);
        i0 = 4u * (unsigned)(t + 2 * NT);
        put(v2.x, i0); put(v2.y, i0 + 1u); put(v2.z, i0 + 2u); put(v2.w, i0 + 3u);
        if (has3) {
            i0 = 4u * (unsigned)(t + 3 * NT);
            put(v3.x, i0); put(v3.y, i0 + 1u); put(v3.z, i0 + 2u); put(v3.w, i0 + 3u);
        }
    }
    __syncthreads();
    const unsigned cnt = s_b[3];
    bool fb = (cnt > CAP);

    if (!fb) {
        // 256-bin sub-histogram over composite bits 31:24 (key bits 19:12)
        for (int i = t; i < (int)cnt; i += NT) atomicAdd(&hc[cand[i] >> 24], 1u);
        __syncthreads();
        const unsigned sc = hc[t];        // thread t owns sub-bin t
        const unsigned Sic = wscan(sc);
        if (lane == 63) s_warp[wid] = Sic;
        hc[t] = 0;                        // re-clear for next caller
        if (t == 0) s_b[5] = 0;
        __syncthreads();
        unsigned crossc = 0;
        for (int w2 = 0; w2 < wid; ++w2) crossc += s_warp[w2];
        const unsigned cdf2 = crossc + Sic - sc;
        bool hit; unsigned m2c = 0;
        if (fromTop) {
            const unsigned suf2 = cnt - cdf2 - sc;
            hit = (suf2 < m1 && m1 <= suf2 + sc);
            if (hit) m2c = m1 - suf2;
        } else {
            hit = (cdf2 < m1 && m1 <= cdf2 + sc);
            if (hit) m2c = m1 - cdf2;
        }
        if (hit) { s_b[0] = (unsigned)t; s_b[1] = m2c; }
        __syncthreads();
        const unsigned b2 = s_b[0];
        const unsigned m2 = s_b[1];
        unsigned* tiny = s_h + O_TINY;
        for (int i = t; i < (int)cnt; i += NT) {
            const unsigned cc = cand[i];
            if ((cc >> 24) == b2) { const unsigned p = atomicAdd(&s_b[5], 1u); if (p < CAP2) tiny[p] = cc; }
        }
        __syncthreads();
        const unsigned c2 = s_b[5];
        if (c2 > CAP2) fb = true;
        else {
            if (t < (int)c2) {            // tie-set rank (c2 == 1 common case)
                const unsigned ci = tiny[t];
                const unsigned di = fromTop ? (ci ^ 0xFFFu) : ci;
                unsigned r = 1;
                for (unsigned j = 0; j < c2; ++j) {
                    const unsigned dj = fromTop ? (tiny[j] ^ 0xFFFu) : tiny[j];
                    if (fromTop ? (dj > di) : (dj < di)) r++;
                }
                if (r == m2) s_b[2] = ci;
            }
            __syncthreads();
        }
    }

    if (fb) {  // pathological fallback: bin-filtered counting rank, global row
        for (int j = t; j < HW; j += NT) {
            const unsigned k = gx[j] & 0x7fffffffu;
            if ((k >> 20) != b0) continue;
            unsigned Ci = ((k & 0xFFFFFu) << 12) | (unsigned)j;
            if (fromTop) Ci ^= 0xFFFu;
            unsigned r = 1;
            for (int j2 = 0; j2 < HW; ++j2) {
                const unsigned k2 = gx[j2] & 0x7fffffffu;
                if ((k2 >> 20) != b0) continue;
                unsigned Cj = ((k2 & 0xFFFFFu) << 12) | (unsigned)j2;
                if (fromTop) Cj ^= 0xFFFu;
                if (fromTop ? (Cj > Ci) : (Cj < Ci)) r++;
            }
            if (r == m1) s_b[2] = ((k & 0xFFFFFu) << 12) | (unsigned)j;
        }
        __syncthreads();
    }
    return s_b[2];
}

extern "C" __global__ void __launch_bounds__(NT)
topk_kernel(const float* __restrict__ x, float* __restrict__ out) {
    __shared__ unsigned s_h[2048];   // 8192 B: hist -> cand/hc/tiny reuse
    __shared__ unsigned s_warp[4];
    __shared__ unsigned s_b[8];

    const int t = threadIdx.x;
    const int lane = t & 63;
    const int wid = t >> 6;
    const int row = blockIdx.x;
    const uint4* __restrict__ xin = (const uint4*)(x + (size_t)row * HW);
    uint4* __restrict__ xout = (uint4*)(out + (size_t)row * HW);
    const unsigned* __restrict__ gx = (const unsigned*)xin;

    {   // clear histogram
        const uint4 z = make_uint4(0u, 0u, 0u, 0u);
        ((uint4*)s_h)[t] = z;
        ((uint4*)s_h)[t + NT] = z;
    }
    __syncthreads();

    // load row into REGISTERS (coalesced) + 2048-bin histogram (bits 30:20)
    const bool has3 = (t < NW4 - 3 * NT);   // t < 16
    const uint4 v0 = xin[t];
    const uint4 v1 = xin[t + NT];
    const uint4 v2 = xin[t + 2 * NT];
    const uint4 v3 = has3 ? xin[t + 3 * NT] : make_uint4(0u, 0u, 0u, 0u);
    atomicAdd(&s_h[(v0.x & 0x7fffffffu) >> 20], 1u);
    atomicAdd(&s_h[(v0.y & 0x7fffffffu) >> 20], 1u);
    atomicAdd(&s_h[(v0.z & 0x7fffffffu) >> 20], 1u);
    atomicAdd(&s_h[(v0.w & 0x7fffffffu) >> 20], 1u);
    atomicAdd(&s_h[(v1.x & 0x7fffffffu) >> 20], 1u);
    atomicAdd(&s_h[(v1.y & 0x7fffffffu) >> 20], 1u);
    atomicAdd(&s_h[(v1.z & 0x7fffffffu) >> 20], 1u);
    atomicAdd(&s_h[(v1.w & 0x7fffffffu) >> 20], 1u);
    atomicAdd(&s_h[(v2.x & 0x7fffffffu) >> 20], 1u);
    atomicAdd(&s_h[(v2.y & 0x7fffffffu) >> 20], 1u);
    atomicAdd(&s_h[(v2.z & 0x7fffffffu) >> 20], 1u);
    atomicAdd(&s_h[(v2.w & 0x7fffffffu) >> 20], 1u);
    if (has3) {
        atomicAdd(&s_h[(v3.x & 0x7fffffffu) >> 20], 1u);
        atomicAdd(&s_h[(v3.y & 0x7fffffffu) >> 20], 1u);
        atomicAdd(&s_h[(v3.z & 0x7fffffffu) >> 20], 1u);
        atomicAdd(&s_h[(v3.w & 0x7fffffffu) >> 20], 1u);
    }
    __syncthreads();

    // register-resident CDF: thread t owns bins 8t..8t+7
    const uint4 ca = ((const uint4*)s_h)[2 * t];
    const uint4 cb = ((const uint4*)s_h)[2 * t + 1];
    unsigned c[8] = {ca.x, ca.y, ca.z, ca.w, cb.x, cb.y, cb.z, cb.w};
    unsigned pre[8];
    unsigned ssum = 0;
#pragma unroll
    for (int i = 0; i < 8; ++i) { pre[i] = ssum; ssum += c[i]; }
    const unsigned Si = wscan(ssum);
    if (lane == 63) s_warp[wid] = Si;
    __syncthreads();
    unsigned cross = 0;
    for (int w2 = 0; w2 < wid; ++w2) cross += s_warp[w2];
    const unsigned base = cross + Si - ssum;   // exclusive CDF of bin 8t

    // clear hc region + counters; locate A (register check) — one phase
    s_h[O_HC + t] = 0;
    if (t == 0) { s_b[3] = 0; s_b[5] = 0; }
#pragma unroll
    for (int i = 0; i < 8; ++i) {
        const unsigned cdfb = base + pre[i];
        const unsigned suf = HW - cdfb - c[i];   // # elements in higher bins
        if (suf < KSEL && KSEL <= suf + c[i]) {
            s_b[0] = 8u * (unsigned)t + (unsigned)i;
            s_b[1] = KSEL - suf;
        }
    }
    __syncthreads();
    const unsigned b0A = s_b[0];
    const unsigned m1A = s_b[1];
    const unsigned compA =
        select_finish<true>(v0, v1, v2, v3, has3, gx, s_h, s_warp, s_b, b0A, m1A);
    const unsigned tIdx = compA & 0xFFFu;

    if (tIdx == 0) {   // keep nothing
        const uint4 z = make_uint4(0u, 0u, 0u, 0u);
        xout[t] = z; xout[t + NT] = z; xout[t + 2 * NT] = z;
        if (has3) xout[t + 3 * NT] = z;
        return;
    }

    // re-zero counters + locate B (register check) — one phase, no extra barrier
    if (t == 0) { s_b[3] = 0; s_b[5] = 0; }
#pragma unroll
    for (int i = 0; i < 8; ++i) {
        const unsigned cdfb = base + pre[i];
        if (cdfb < tIdx && tIdx <= cdfb + c[i]) {
            s_b[0] = 8u * (unsigned)t + (unsigned)i;
            s_b[1] = tIdx - cdfb;
        }
    }
    __syncthreads();
    const unsigned b0B = s_b[0];
    const unsigned m1B = s_b[1];
    const unsigned compB =
        select_finish<false>(v0, v1, v2, v3, has3, gx, s_h, s_warp, s_b, b0B, m1B);
    const unsigned KB = (b0B << 20) | (compB >> 12);
    const unsigned eB = compB & 0xFFFu;

    // final mask + store from registers: keep = k < KB || (k == KB && idx <= eB)
    {
        auto msk = [&](unsigned w, unsigned idx) -> unsigned {
            const unsigned k = w & 0x7fffffffu;
            return (k < KB || (k == KB && idx <= eB)) ? w : 0u;
        };
        uint4 o;
        unsigned i0 = 4u * (unsigned)t;
        o.x = msk(v0.x, i0); o.y = msk(v0.y, i0 + 1u);
        o.z = msk(v0.z, i0 + 2u); o.w = msk(v0.w, i0 + 3u);
        xout[t] = o;
        i0 = 4u * (unsigned)(t + NT);
        o.x = msk(v1.x, i0); o.y = msk(v1.y, i0 + 1u);
        o.z = msk(v1.z, i0 + 2u); o.w = msk(v1.w, i0 + 3u);
        xout[t + NT] = o;
        i0 = 4u * (unsigned)(t + 2 * NT);
        o.x = msk(v2.x, i0); o.y = msk(v2.y, i0 + 1u);
        o.z = msk(v2.z, i0 + 2u); o.w = msk(v2.w, i0 + 3u);
        xout[t + 2 * NT] = o;
        if (has3) {
            i0 = 4u * (unsigned)(t + 3 * NT);
            o.x = msk(v3.x, i0); o.y = msk(v3.y, i0 + 1u);
            o.z = msk(v3.z, i0 + 2u); o.w = msk(v3.w, i0 + 3u);
            xout[t + 3 * NT] = o;
        }
    }
}

extern "C" void kernel_launch(void* const* d_in, const int* in_sizes, int n_in,
                              void* d_out, int out_size, void* d_ws, size_t ws_size,
                              hipStream_t stream) {
    const float* x = (const float*)d_in[0];
    float* out = (float*)d_out;
    const int rows = in_sizes[0] / HW;  // 8192
    topk_kernel<<<dim3(rows), dim3(NT), 0, stream>>>(x, out);
}